// Round 5
// baseline (189.546 us; speedup 1.0000x reference)
//
#include <hip/hip_runtime.h>

typedef __attribute__((ext_vector_type(8))) short bf16x8;
typedef __attribute__((ext_vector_type(4))) float f32x4;
typedef __attribute__((ext_vector_type(4))) unsigned int u32x4;
typedef __attribute__((ext_vector_type(4))) unsigned short u16x4;

#define H_ 16
#define B_ 2
#define T_ 2048
#define DH_ 64
#define MD_ 1024

static __device__ inline unsigned short f2bf(float f) {  // round-nearest-even
    union { float f; unsigned u; } x; x.f = f;
    unsigned r = (x.u + 0x7fffu + ((x.u >> 16) & 1u)) >> 16;
    return (unsigned short)r;
}
// pack two fp32 -> two bf16 (truncation), lo in low short. 1 v_perm_b32.
static __device__ inline unsigned int pack_bf2(float lo, float hi) {
    return __builtin_amdgcn_perm(__float_as_uint(hi), __float_as_uint(lo), 0x07060302u);
}
static __device__ inline unsigned short hi16(float f) {
    return (unsigned short)(__float_as_uint(f) >> 16);
}

// ---------------------------------------------------------------------------
// Kernel 1: prep. blocks 0..1023: Wo fp32->bf16 (RNE). 1024..2047: K fp32->bf16
// (trunc, same layout). 2048..3071: V fp32 -> V^T bf16 [hb][dh][T] via LDS.
// ---------------------------------------------------------------------------
__global__ __launch_bounds__(256) void prep_k(const float* __restrict__ k,
                                              const float* __restrict__ v,
                                              const float* __restrict__ w,
                                              unsigned short* __restrict__ kb,
                                              unsigned short* __restrict__ vtb,
                                              unsigned short* __restrict__ wob) {
    __shared__ __attribute__((aligned(16))) unsigned short vt64[64][64];
    const int blk = blockIdx.x;
    const int tid = threadIdx.x;
    if (blk < 1024) {
        int i = (blk * 256 + tid) * 4;
        f32x4 x = *(const f32x4*)(w + i);
        u16x4 y;
        y[0] = f2bf(x[0]); y[1] = f2bf(x[1]); y[2] = f2bf(x[2]); y[3] = f2bf(x[3]);
        *(u16x4*)(wob + i) = y;
    } else if (blk < 2048) {
        int j = blk - 1024;
        const int hb = j >> 5, s0 = (j & 31) * 64;
        const int row = tid >> 2, c = (tid & 3) * 16;
        const long off = (long)hb * (T_ * DH_) + (long)(s0 + row) * DH_ + c;
        const float* p = k + off;
        f32x4 a0 = *(const f32x4*)p;
        f32x4 a1 = *(const f32x4*)(p + 4);
        f32x4 a2 = *(const f32x4*)(p + 8);
        f32x4 a3 = *(const f32x4*)(p + 12);
        u32x4 w0, w1;
        w0[0] = pack_bf2(a0[0], a0[1]); w0[1] = pack_bf2(a0[2], a0[3]);
        w0[2] = pack_bf2(a1[0], a1[1]); w0[3] = pack_bf2(a1[2], a1[3]);
        w1[0] = pack_bf2(a2[0], a2[1]); w1[1] = pack_bf2(a2[2], a2[3]);
        w1[2] = pack_bf2(a3[0], a3[1]); w1[3] = pack_bf2(a3[2], a3[3]);
        *(u32x4*)(kb + off) = w0;
        *(u32x4*)(kb + off + 8) = w1;
    } else {
        int j = blk - 2048;
        const int hb = j >> 5, s0 = (j & 31) * 64;
        const int vkp = tid & 31, vdg = tid >> 5;  // key-pair, dh-group
        const float* vp = v + (long)hb * (T_ * DH_) + (long)(s0 + 2 * vkp) * DH_ + vdg * 8;
        f32x4 va0 = *(const f32x4*)vp;
        f32x4 va1 = *(const f32x4*)(vp + 4);
        f32x4 vb0 = *(const f32x4*)(vp + DH_);
        f32x4 vb1 = *(const f32x4*)(vp + DH_ + 4);
#pragma unroll
        for (int jj = 0; jj < 4; jj++) {
            ((unsigned int*)&vt64[vdg * 8 + jj][0])[vkp]     = pack_bf2(va0[jj], vb0[jj]);
            ((unsigned int*)&vt64[vdg * 8 + 4 + jj][0])[vkp] = pack_bf2(va1[jj], vb1[jj]);
        }
        __syncthreads();
        const int dh = tid >> 2, kc = (tid & 3) * 16;
        u32x4 o0 = *(const u32x4*)&vt64[dh][kc];
        u32x4 o1 = *(const u32x4*)&vt64[dh][kc + 8];
        unsigned short* op = vtb + (long)hb * (DH_ * T_) + (long)dh * T_ + s0 + kc;
        *(u32x4*)op = o0;
        *(u32x4*)(op + 8) = o1;
    }
}

// ---------------------------------------------------------------------------
// Kernel 2: barrier-free causal attention. One wave = one 32-row q-tile;
// the block's two waves split the key range by step-parity (additive merge:
// no-max softmax => O = O0+O1, l = l0+l1). K/V fragments read directly from
// L2-resident kb/vtb (no LDS staging, no K-loop barriers). P round-trips
// through a per-wave LDS buffer. l via ones-MFMA. Longest q-tiles first.
// 2048 blocks x 128 thr; target 8 blocks/CU.
// ---------------------------------------------------------------------------
__global__ __launch_bounds__(128, 4) void attn_k(const float* __restrict__ q,
                                                 const unsigned short* __restrict__ kb,
                                                 const unsigned short* __restrict__ vtb,
                                                 unsigned short* __restrict__ ctx) {
    const int bl = blockIdx.x;
    const int xcd = bl & 7, s = bl >> 3;      // round-robin: 4 hb per XCD
    const int hb = xcd * 4 + (s & 3);
    const int qt = 63 - (s >> 2);             // longest-first for tail packing
    const int h = hb >> 1, b = hb & 1;
    const int tid = threadIdx.x;
    const int w = tid >> 6, lane = tid & 63;
    const int ln = lane & 15, quad = lane >> 4;

    __shared__ __attribute__((aligned(16))) unsigned short pl[2][32][72]; // per-wave P
    __shared__ __attribute__((aligned(16))) float po[32][64];             // wave1 partial O
    __shared__ float cl[32];                                              // wave1 partial l

    const long kbase = (long)hb * (T_ * DH_);
    const long vbase = (long)hb * (DH_ * T_);
    const int nsteps = (qt >> 1) + 1;
    const int qrow0 = qt * 32;

    bf16x8 ones;
#pragma unroll
    for (int z = 0; z < 8; z++) ones[z] = (short)0x3F80;

    // Q fragments, 2 row-groups (RNE, 1/sqrt(64) folded)
    bf16x8 qf[2][2];
#pragma unroll
    for (int rf = 0; rf < 2; rf++) {
        const float* qp = q + kbase + (long)(qrow0 + rf * 16 + ln) * DH_ + quad * 8;
        f32x4 a0 = *(const f32x4*)qp;
        f32x4 a1 = *(const f32x4*)(qp + 4);
        f32x4 b0 = *(const f32x4*)(qp + 32);
        f32x4 b1 = *(const f32x4*)(qp + 36);
#pragma unroll
        for (int z = 0; z < 4; z++) {
            qf[rf][0][z]     = (short)f2bf(a0[z] * 0.125f);
            qf[rf][0][4 + z] = (short)f2bf(a1[z] * 0.125f);
            qf[rf][1][z]     = (short)f2bf(b0[z] * 0.125f);
            qf[rf][1][4 + z] = (short)f2bf(b1[z] * 0.125f);
        }
    }

    f32x4 oacc[2][4];
#pragma unroll
    for (int rf = 0; rf < 2; rf++)
#pragma unroll
        for (int dt = 0; dt < 4; dt++) oacc[rf][dt] = f32x4{0.f, 0.f, 0.f, 0.f};
    f32x4 lacc[2];
    lacc[0] = f32x4{0.f, 0.f, 0.f, 0.f};
    lacc[1] = f32x4{0.f, 0.f, 0.f, 0.f};

#pragma unroll 1
    for (int sg = w; sg < nsteps; sg += 2) {
        const int s0 = sg * 64;
        const bool last = (sg == nsteps - 1);
        const bool halfstep = last && !(qt & 1);  // upper 32 keys fully masked

        // QK^T + exp + P-store, fully unrolled (wave-uniform skip on halfstep)
#pragma unroll
        for (int nt = 0; nt < 4; nt++) {
            if (halfstep && nt >= 2) continue;
            const unsigned short* kp = kb + kbase + (long)(s0 + nt * 16 + ln) * DH_ + quad * 8;
            bf16x8 kf0 = *(const bf16x8*)kp;
            bf16x8 kf1 = *(const bf16x8*)(kp + 32);
            f32x4 s0a = f32x4{0.f, 0.f, 0.f, 0.f};
            f32x4 s1a = f32x4{0.f, 0.f, 0.f, 0.f};
            s0a = __builtin_amdgcn_mfma_f32_16x16x32_bf16(qf[0][0], kf0, s0a, 0, 0, 0);
            s0a = __builtin_amdgcn_mfma_f32_16x16x32_bf16(qf[0][1], kf1, s0a, 0, 0, 0);
            s1a = __builtin_amdgcn_mfma_f32_16x16x32_bf16(qf[1][0], kf0, s1a, 0, 0, 0);
            s1a = __builtin_amdgcn_mfma_f32_16x16x32_bf16(qf[1][1], kf1, s1a, 0, 0, 0);
            const int colg = s0 + nt * 16 + ln;
            if (last) {
#pragma unroll
                for (int r = 0; r < 4; r++) {
                    float p0 = __expf(s0a[r]);
                    if (colg > qrow0 + quad * 4 + r) p0 = 0.f;
                    pl[w][quad * 4 + r][nt * 16 + ln] = hi16(p0);
                    float p1 = __expf(s1a[r]);
                    if (colg > qrow0 + 16 + quad * 4 + r) p1 = 0.f;
                    pl[w][16 + quad * 4 + r][nt * 16 + ln] = hi16(p1);
                }
            } else {
#pragma unroll
                for (int r = 0; r < 4; r++) {
                    pl[w][quad * 4 + r][nt * 16 + ln]      = hi16(__expf(s0a[r]));
                    pl[w][16 + quad * 4 + r][nt * 16 + ln] = hi16(__expf(s1a[r]));
                }
            }
        }

        // P (A-layout) + V fragments -> PV and l (in-wave LDS ordering, no barrier)
#pragma unroll
        for (int hf = 0; hf < 2; hf++) {
            if (halfstep && hf >= 1) continue;
            bf16x8 pf0 = *(const bf16x8*)&pl[w][ln][hf * 32 + quad * 8];
            bf16x8 pf1 = *(const bf16x8*)&pl[w][16 + ln][hf * 32 + quad * 8];
            lacc[0] = __builtin_amdgcn_mfma_f32_16x16x32_bf16(pf0, ones, lacc[0], 0, 0, 0);
            lacc[1] = __builtin_amdgcn_mfma_f32_16x16x32_bf16(pf1, ones, lacc[1], 0, 0, 0);
#pragma unroll
            for (int dt = 0; dt < 4; dt++) {
                const unsigned short* vp = vtb + vbase + (long)(dt * 16 + ln) * T_ + s0 + hf * 32 + quad * 8;
                bf16x8 vf = *(const bf16x8*)vp;
                oacc[0][dt] = __builtin_amdgcn_mfma_f32_16x16x32_bf16(pf0, vf, oacc[0][dt], 0, 0, 0);
                oacc[1][dt] = __builtin_amdgcn_mfma_f32_16x16x32_bf16(pf1, vf, oacc[1][dt], 0, 0, 0);
            }
        }
    }

    // additive combine: wave1 -> LDS, wave0 finalizes
    if (w == 1) {
#pragma unroll
        for (int rf = 0; rf < 2; rf++)
#pragma unroll
            for (int dt = 0; dt < 4; dt++)
#pragma unroll
                for (int r = 0; r < 4; r++)
                    po[rf * 16 + quad * 4 + r][dt * 16 + ln] = oacc[rf][dt][r];
        if (ln == 0) {
#pragma unroll
            for (int rf = 0; rf < 2; rf++)
#pragma unroll
                for (int r = 0; r < 4; r++)
                    cl[rf * 16 + quad * 4 + r] = lacc[rf][r];
        }
    }
    __syncthreads();
    if (w == 0) {
        unsigned short* cp = ctx + (long)(b * T_ + qrow0) * MD_ + h * 64;
#pragma unroll
        for (int rf = 0; rf < 2; rf++)
#pragma unroll
            for (int r = 0; r < 4; r++) {
                const int row = rf * 16 + quad * 4 + r;
                float l = lacc[rf][r] + cl[row];
                float rl = __builtin_amdgcn_rcpf(l);
#pragma unroll
                for (int dt = 0; dt < 4; dt++) {
                    float o = oacc[rf][dt][r] + po[row][dt * 16 + ln];
                    cp[(long)row * MD_ + dt * 16 + ln] = f2bf(o * rl);
                }
            }
    }
}

// ---------------------------------------------------------------------------
// Kernel 3: projection GEMM. out[m][n] = ctx[m][:] . Wo[n][:] + bias[n]
// M=4096 N=1024 K=1024. BM=64 BN=64 BK=128 -> 1024 blocks (4/CU), 8 iters,
// 16 MFMAs/wave per barrier-pair, reg-prefetch. Each thread stages a FULL
// 32-column slice (4 x u32x4) -- fixes the R4 half-staged-tile NaN bug.
// ---------------------------------------------------------------------------
__global__ __launch_bounds__(256, 4) void proj_k(const unsigned short* __restrict__ A,
                                                 const unsigned short* __restrict__ Bw,
                                                 const float* __restrict__ bias,
                                                 float* __restrict__ out) {
    const int i = blockIdx.x;
    const int n0 = ((i & 7) * 2 + ((i >> 3) & 1)) * 64;
    const int m0 = (i >> 4) * 64;
    const int tid = threadIdx.x;
    const int wave = tid >> 6, lane = tid & 63;
    const int wm = wave >> 1, wn = wave & 1;
    const int ln = lane & 15, quad = lane >> 4;

    __shared__ __attribute__((aligned(16))) unsigned short As[64][136];
    __shared__ __attribute__((aligned(16))) unsigned short Bs[64][136];

    const int srow = tid >> 2, sc = (tid & 3) * 32;

    f32x4 acc[2][2];
#pragma unroll
    for (int a = 0; a < 2; a++)
#pragma unroll
        for (int c = 0; c < 2; c++) acc[a][c] = f32x4{0.f, 0.f, 0.f, 0.f};

    u32x4 ar[4], br[4];
    {
        const unsigned short* ap = A + (long)(m0 + srow) * 1024 + sc;
        const unsigned short* bp = Bw + (long)(n0 + srow) * 1024 + sc;
#pragma unroll
        for (int z = 0; z < 4; z++) {
            ar[z] = *(const u32x4*)(ap + z * 8);
            br[z] = *(const u32x4*)(bp + z * 8);
        }
    }

#pragma unroll 1
    for (int ks = 0; ks < 1024; ks += 128) {
        __syncthreads();
#pragma unroll
        for (int z = 0; z < 4; z++) {
            *(u32x4*)&As[srow][sc + z * 8] = ar[z];
            *(u32x4*)&Bs[srow][sc + z * 8] = br[z];
        }
        __syncthreads();

        if (ks + 128 < 1024) {
            const unsigned short* ap = A + (long)(m0 + srow) * 1024 + ks + 128 + sc;
            const unsigned short* bp = Bw + (long)(n0 + srow) * 1024 + ks + 128 + sc;
#pragma unroll
            for (int z = 0; z < 4; z++) {
                ar[z] = *(const u32x4*)(ap + z * 8);
                br[z] = *(const u32x4*)(bp + z * 8);
            }
        }

#pragma unroll
        for (int kk = 0; kk < 4; kk++) {
            bf16x8 af0 = *(const bf16x8*)&As[wm * 32 + ln][kk * 32 + quad * 8];
            bf16x8 af1 = *(const bf16x8*)&As[wm * 32 + 16 + ln][kk * 32 + quad * 8];
            bf16x8 bf0 = *(const bf16x8*)&Bs[wn * 32 + ln][kk * 32 + quad * 8];
            bf16x8 bf1 = *(const bf16x8*)&Bs[wn * 32 + 16 + ln][kk * 32 + quad * 8];
            acc[0][0] = __builtin_amdgcn_mfma_f32_16x16x32_bf16(af0, bf0, acc[0][0], 0, 0, 0);
            acc[0][1] = __builtin_amdgcn_mfma_f32_16x16x32_bf16(af0, bf1, acc[0][1], 0, 0, 0);
            acc[1][0] = __builtin_amdgcn_mfma_f32_16x16x32_bf16(af1, bf0, acc[1][0], 0, 0, 0);
            acc[1][1] = __builtin_amdgcn_mfma_f32_16x16x32_bf16(af1, bf1, acc[1][1], 0, 0, 0);
        }
    }

#pragma unroll
    for (int nt = 0; nt < 2; nt++) {
        int col = n0 + wn * 32 + nt * 16 + ln;
        float bz = bias[col];
#pragma unroll
        for (int mt = 0; mt < 2; mt++)
#pragma unroll
            for (int r = 0; r < 4; r++) {
                int row = m0 + wm * 32 + mt * 16 + quad * 4 + r;
                out[(long)row * 1024 + col] = acc[mt][nt][r] + bz;
            }
    }
}

extern "C" void kernel_launch(void* const* d_in, const int* in_sizes, int n_in,
                              void* d_out, int out_size, void* d_ws, size_t ws_size,
                              hipStream_t stream) {
    const float* q    = (const float*)d_in[0];
    const float* k    = (const float*)d_in[1];
    const float* v    = (const float*)d_in[2];
    const float* Wo_w = (const float*)d_in[3];
    const float* Wo_b = (const float*)d_in[4];
    float* out = (float*)d_out;

    unsigned short* ctx = (unsigned short*)d_ws;           // [4096][1024]  8 MB
    unsigned short* wob = ctx + (size_t)4096 * 1024;       // [1024][1024]  2 MB
    unsigned short* kbb = wob + (size_t)1024 * 1024;       // [32][2048][64] 8.4 MB
    unsigned short* vtb = kbb + (size_t)32 * 2048 * 64;    // [32][64][2048] 8.4 MB

    prep_k<<<3072, 256, 0, stream>>>(k, v, Wo_w, kbb, vtb, wob);
    attn_k<<<2048, 128, 0, stream>>>(q, kbb, vtb, ctx);
    proj_k<<<1024, 256, 0, stream>>>(ctx, wob, Wo_b, out);
}

// Round 6
// 165.309 us; speedup vs baseline: 1.1466x; 1.1466x over previous
//
#include <hip/hip_runtime.h>

typedef __attribute__((ext_vector_type(8))) short bf16x8;
typedef __attribute__((ext_vector_type(4))) float f32x4;
typedef __attribute__((ext_vector_type(4))) unsigned int u32x4;
typedef __attribute__((ext_vector_type(4))) unsigned short u16x4;

#define H_ 16
#define B_ 2
#define T_ 2048
#define DH_ 64
#define MD_ 1024

static __device__ inline unsigned short f2bf(float f) {  // round-nearest-even
    union { float f; unsigned u; } x; x.f = f;
    unsigned r = (x.u + 0x7fffu + ((x.u >> 16) & 1u)) >> 16;
    return (unsigned short)r;
}
// pack two fp32 -> two bf16 (truncation), lo in low short. 1 v_perm_b32.
static __device__ inline unsigned int pack_bf2(float lo, float hi) {
    return __builtin_amdgcn_perm(__float_as_uint(hi), __float_as_uint(lo), 0x07060302u);
}
static __device__ inline unsigned short hi16(float f) {
    return (unsigned short)(__float_as_uint(f) >> 16);
}

// ---------------------------------------------------------------------------
// Kernel 1: prep. blocks 0..1023: Wo fp32->bf16 (RNE). 1024..2047: K fp32->bf16
// (trunc, same layout). 2048..3071: V fp32 -> V^T bf16 [hb][dh][T] via LDS.
// ---------------------------------------------------------------------------
__global__ __launch_bounds__(256) void prep_k(const float* __restrict__ k,
                                              const float* __restrict__ v,
                                              const float* __restrict__ w,
                                              unsigned short* __restrict__ kb,
                                              unsigned short* __restrict__ vtb,
                                              unsigned short* __restrict__ wob) {
    __shared__ __attribute__((aligned(16))) unsigned short vt64[64][64];
    const int blk = blockIdx.x;
    const int tid = threadIdx.x;
    if (blk < 1024) {
        int i = (blk * 256 + tid) * 4;
        f32x4 x = *(const f32x4*)(w + i);
        u16x4 y;
        y[0] = f2bf(x[0]); y[1] = f2bf(x[1]); y[2] = f2bf(x[2]); y[3] = f2bf(x[3]);
        *(u16x4*)(wob + i) = y;
    } else if (blk < 2048) {
        int j = blk - 1024;
        const int hb = j >> 5, s0 = (j & 31) * 64;
        const int row = tid >> 2, c = (tid & 3) * 16;
        const long off = (long)hb * (T_ * DH_) + (long)(s0 + row) * DH_ + c;
        const float* p = k + off;
        f32x4 a0 = *(const f32x4*)p;
        f32x4 a1 = *(const f32x4*)(p + 4);
        f32x4 a2 = *(const f32x4*)(p + 8);
        f32x4 a3 = *(const f32x4*)(p + 12);
        u32x4 w0, w1;
        w0[0] = pack_bf2(a0[0], a0[1]); w0[1] = pack_bf2(a0[2], a0[3]);
        w0[2] = pack_bf2(a1[0], a1[1]); w0[3] = pack_bf2(a1[2], a1[3]);
        w1[0] = pack_bf2(a2[0], a2[1]); w1[1] = pack_bf2(a2[2], a2[3]);
        w1[2] = pack_bf2(a3[0], a3[1]); w1[3] = pack_bf2(a3[2], a3[3]);
        *(u32x4*)(kb + off) = w0;
        *(u32x4*)(kb + off + 8) = w1;
    } else {
        int j = blk - 2048;
        const int hb = j >> 5, s0 = (j & 31) * 64;
        const int vkp = tid & 31, vdg = tid >> 5;  // key-pair, dh-group
        const float* vp = v + (long)hb * (T_ * DH_) + (long)(s0 + 2 * vkp) * DH_ + vdg * 8;
        f32x4 va0 = *(const f32x4*)vp;
        f32x4 va1 = *(const f32x4*)(vp + 4);
        f32x4 vb0 = *(const f32x4*)(vp + DH_);
        f32x4 vb1 = *(const f32x4*)(vp + DH_ + 4);
#pragma unroll
        for (int jj = 0; jj < 4; jj++) {
            ((unsigned int*)&vt64[vdg * 8 + jj][0])[vkp]     = pack_bf2(va0[jj], vb0[jj]);
            ((unsigned int*)&vt64[vdg * 8 + 4 + jj][0])[vkp] = pack_bf2(va1[jj], vb1[jj]);
        }
        __syncthreads();
        const int dh = tid >> 2, kc = (tid & 3) * 16;
        u32x4 o0 = *(const u32x4*)&vt64[dh][kc];
        u32x4 o1 = *(const u32x4*)&vt64[dh][kc + 8];
        unsigned short* op = vtb + (long)hb * (DH_ * T_) + (long)dh * T_ + s0 + kc;
        *(u32x4*)op = o0;
        *(u32x4*)(op + 8) = o1;
    }
}

// ---------------------------------------------------------------------------
// Kernel 2: causal attention, R3 LDS-staged body + split-K x2 scheduling.
// Job = (hb, 64-row q-tile t, parity j): processes 64-key steps sg=j,j+2,...
// No-max softmax is additive, so each job writes partial O (bf16) + partial l
// (fp32) to ws; merge happens in proj's A-staging. 2048 jobs x 256 thr,
// longest-first (t descending with blockIdx) -> dynamic CU refill.
// ---------------------------------------------------------------------------
__global__ __launch_bounds__(256, 5) void attn_k(const float* __restrict__ q,
                                                 const unsigned short* __restrict__ kb,
                                                 const unsigned short* __restrict__ vtb,
                                                 unsigned short* __restrict__ pbuf,
                                                 float* __restrict__ lbuf) {
    const int bl = blockIdx.x;
    const int t = 31 - (bl >> 6);             // longest jobs dispatched first
    const int inner = bl & 63;
    const int hb = inner >> 1, j = inner & 1;
    const int tid = threadIdx.x;
    const int wave = tid >> 6, lane = tid & 63;
    const int ln = lane & 15, quad = lane >> 4;

    __shared__ __attribute__((aligned(16))) unsigned short kt[64][72];    // [key][dh]
    __shared__ __attribute__((aligned(16))) unsigned short vt[64][72];    // [dh][key]
    __shared__ __attribute__((aligned(16))) unsigned short pl[4][16][72]; // per-wave P

    const long kbase = (long)hb * (T_ * DH_);
    const long vbase = (long)hb * (DH_ * T_);
    const int nsteps = t + 1;
    const int q0w = t * 64 + wave * 16;
    const int srow = tid >> 2, sc = (tid & 3) * 16;

    bf16x8 ones;
#pragma unroll
    for (int z = 0; z < 8; z++) ones[z] = (short)0x3F80;

    // Q fragment (RNE, 1/sqrt(64) folded)
    bf16x8 qf0, qf1;
    {
        const float* qp = q + kbase + (long)(q0w + ln) * DH_ + quad * 8;
        f32x4 a0 = *(const f32x4*)qp;
        f32x4 a1 = *(const f32x4*)(qp + 4);
        f32x4 b0 = *(const f32x4*)(qp + 32);
        f32x4 b1 = *(const f32x4*)(qp + 36);
#pragma unroll
        for (int z = 0; z < 4; z++) {
            qf0[z]   = (short)f2bf(a0[z] * 0.125f);
            qf0[4+z] = (short)f2bf(a1[z] * 0.125f);
            qf1[z]   = (short)f2bf(b0[z] * 0.125f);
            qf1[4+z] = (short)f2bf(b1[z] * 0.125f);
        }
    }

    f32x4 oacc[4];
#pragma unroll
    for (int z = 0; z < 4; z++) oacc[z] = f32x4{0.f, 0.f, 0.f, 0.f};
    f32x4 lacc = f32x4{0.f, 0.f, 0.f, 0.f};

    // prefetch first owned step (sg = j)
    u32x4 kr0, kr1, vr0, vr1;
    if (j < nsteps) {
        const unsigned short* kp = kb + kbase + (long)(j * 64 + srow) * DH_ + sc;
        kr0 = *(const u32x4*)kp; kr1 = *(const u32x4*)(kp + 8);
        const unsigned short* vp = vtb + vbase + (long)srow * T_ + j * 64 + sc;
        vr0 = *(const u32x4*)vp; vr1 = *(const u32x4*)(vp + 8);
    }

#pragma unroll 1
    for (int sg = j; sg < nsteps; sg += 2) {
        const int s0 = sg * 64;
        __syncthreads();
        *(u32x4*)&kt[srow][sc]     = kr0;
        *(u32x4*)&kt[srow][sc + 8] = kr1;
        *(u32x4*)&vt[srow][sc]     = vr0;
        *(u32x4*)&vt[srow][sc + 8] = vr1;
        __syncthreads();

        if (sg + 2 < nsteps) {
            const unsigned short* kp = kb + kbase + (long)((sg + 2) * 64 + srow) * DH_ + sc;
            kr0 = *(const u32x4*)kp; kr1 = *(const u32x4*)(kp + 8);
            const unsigned short* vp = vtb + vbase + (long)srow * T_ + (sg + 2) * 64 + sc;
            vr0 = *(const u32x4*)vp; vr1 = *(const u32x4*)(vp + 8);
        }

        // QK^T: 4 key-subtiles x K=64
        f32x4 sa[4];
#pragma unroll
        for (int nt = 0; nt < 4; nt++) {
            bf16x8 kf0 = *(const bf16x8*)&kt[nt * 16 + ln][quad * 8];
            bf16x8 kf1 = *(const bf16x8*)&kt[nt * 16 + ln][32 + quad * 8];
            f32x4 a = f32x4{0.f, 0.f, 0.f, 0.f};
            a = __builtin_amdgcn_mfma_f32_16x16x32_bf16(qf0, kf0, a, 0, 0, 0);
            a = __builtin_amdgcn_mfma_f32_16x16x32_bf16(qf1, kf1, a, 0, 0, 0);
            sa[nt] = a;
        }

        // p = exp(s); mask only on the diagonal step (wave-uniform branch)
        if (sg == nsteps - 1) {
            const int lr = wave * 16 + quad * 4;
#pragma unroll
            for (int nt = 0; nt < 4; nt++)
#pragma unroll
                for (int r = 0; r < 4; r++) {
                    float p = __expf(sa[nt][r]);
                    if (nt * 16 + ln > lr + r) p = 0.f;
                    pl[wave][quad * 4 + r][nt * 16 + ln] = hi16(p);
                }
        } else {
#pragma unroll
            for (int nt = 0; nt < 4; nt++)
#pragma unroll
                for (int r = 0; r < 4; r++)
                    pl[wave][quad * 4 + r][nt * 16 + ln] = hi16(__expf(sa[nt][r]));
        }

        // per-wave buffer: in-wave DS ordering + lgkmcnt, no barrier needed
        bf16x8 pf0 = *(const bf16x8*)&pl[wave][ln][quad * 8];
        bf16x8 pf1 = *(const bf16x8*)&pl[wave][ln][32 + quad * 8];

#pragma unroll
        for (int dt = 0; dt < 4; dt++) {
            bf16x8 vf0 = *(const bf16x8*)&vt[dt * 16 + ln][quad * 8];
            bf16x8 vf1 = *(const bf16x8*)&vt[dt * 16 + ln][32 + quad * 8];
            oacc[dt] = __builtin_amdgcn_mfma_f32_16x16x32_bf16(pf0, vf0, oacc[dt], 0, 0, 0);
            oacc[dt] = __builtin_amdgcn_mfma_f32_16x16x32_bf16(pf1, vf1, oacc[dt], 0, 0, 0);
        }
        // row-sums via ones-MFMA
        lacc = __builtin_amdgcn_mfma_f32_16x16x32_bf16(pf0, ones, lacc, 0, 0, 0);
        lacc = __builtin_amdgcn_mfma_f32_16x16x32_bf16(pf1, ones, lacc, 0, 0, 0);
    }

    // epilogue: write partial O (bf16) + partial l (fp32); merge happens in proj
    const int jb = (hb * 32 + t) * 2 + j;
    unsigned short* op = pbuf + (long)jb * 4096;
#pragma unroll
    for (int r = 0; r < 4; r++) {
        const int row = wave * 16 + quad * 4 + r;
#pragma unroll
        for (int dt = 0; dt < 4; dt++)
            op[row * 64 + dt * 16 + ln] = f2bf(oacc[dt][r]);
    }
    if (ln == 0) {
#pragma unroll
        for (int r = 0; r < 4; r++)
            lbuf[jb * 64 + wave * 16 + quad * 4 + r] = lacc[r];
    }
}

// ---------------------------------------------------------------------------
// Kernel 3: projection GEMM with fused attention-partial merge.
// A[m][c] = (p0[m][c] + p1[m][c]) * rcp(l0[m]+l1[m]) computed during staging.
// M=4096 N=1024 K=1024. BM=64 BN=64 BK=128 -> 1024 blocks (4/CU).
// ---------------------------------------------------------------------------
__global__ __launch_bounds__(256, 4) void proj_k(const unsigned short* __restrict__ pbuf,
                                                 const float* __restrict__ lbuf,
                                                 const unsigned short* __restrict__ Bw,
                                                 const float* __restrict__ bias,
                                                 float* __restrict__ out) {
    const int i = blockIdx.x;
    const int n0 = ((i & 7) * 2 + ((i >> 3) & 1)) * 64;
    const int m0 = (i >> 4) * 64;
    const int tid = threadIdx.x;
    const int wave = tid >> 6, lane = tid & 63;
    const int wm = wave >> 1, wn = wave & 1;
    const int ln = lane & 15, quad = lane >> 4;

    __shared__ __attribute__((aligned(16))) unsigned short As[64][136];
    __shared__ __attribute__((aligned(16))) unsigned short Bs[64][136];

    const int srow = tid >> 2, sc = (tid & 3) * 32;
    const int m = m0 + srow;                   // output row
    const int b = m >> 11, tt = m & 2047;      // batch, seq pos
    const int tile = tt >> 6, r64 = tt & 63;   // 64-row attn tile, row within

    f32x4 acc[2][2];
#pragma unroll
    for (int a = 0; a < 2; a++)
#pragma unroll
        for (int c = 0; c < 2; c++) acc[a][c] = f32x4{0.f, 0.f, 0.f, 0.f};

    // per-ks A-source address helper values (hh/hb change with ks)
    u32x4 p0r[4], p1r[4], br[4];
    float lsum;
    {
        const int hh = sc >> 6;                 // ks = 0
        const int hb = hh * 2 + b;
        const long base = ((long)(hb * 32 + tile) * 2) * 4096 + r64 * 64 + (sc & 63);
#pragma unroll
        for (int z = 0; z < 4; z++) {
            p0r[z] = *(const u32x4*)(pbuf + base + z * 8);
            p1r[z] = *(const u32x4*)(pbuf + base + 4096 + z * 8);
        }
        lsum = lbuf[(hb * 32 + tile) * 128 + r64] + lbuf[(hb * 32 + tile) * 128 + 64 + r64];
        const unsigned short* bp = Bw + (long)(n0 + srow) * 1024 + sc;
#pragma unroll
        for (int z = 0; z < 4; z++) br[z] = *(const u32x4*)(bp + z * 8);
    }

#pragma unroll 1
    for (int ks = 0; ks < 1024; ks += 128) {
        __syncthreads();
        {
            const float rl = __builtin_amdgcn_rcpf(lsum);
#pragma unroll
            for (int z = 0; z < 4; z++) {
                u32x4 c;
#pragma unroll
                for (int w = 0; w < 4; w++) {
                    unsigned a0 = p0r[z][w], a1 = p1r[z][w];
                    float lo = __uint_as_float(a0 << 16) + __uint_as_float(a1 << 16);
                    float hi = __uint_as_float(a0 & 0xffff0000u) + __uint_as_float(a1 & 0xffff0000u);
                    c[w] = pack_bf2(lo * rl, hi * rl);
                }
                *(u32x4*)&As[srow][sc + z * 8] = c;
                *(u32x4*)&Bs[srow][sc + z * 8] = br[z];
            }
        }
        __syncthreads();

        if (ks + 128 < 1024) {
            const int kc = ks + 128 + sc;
            const int hh = kc >> 6;
            const int hb = hh * 2 + b;
            const long base = ((long)(hb * 32 + tile) * 2) * 4096 + r64 * 64 + (kc & 63);
#pragma unroll
            for (int z = 0; z < 4; z++) {
                p0r[z] = *(const u32x4*)(pbuf + base + z * 8);
                p1r[z] = *(const u32x4*)(pbuf + base + 4096 + z * 8);
            }
            lsum = lbuf[(hb * 32 + tile) * 128 + r64] + lbuf[(hb * 32 + tile) * 128 + 64 + r64];
            const unsigned short* bp = Bw + (long)(n0 + srow) * 1024 + ks + 128 + sc;
#pragma unroll
            for (int z = 0; z < 4; z++) br[z] = *(const u32x4*)(bp + z * 8);
        }

#pragma unroll
        for (int kk = 0; kk < 4; kk++) {
            bf16x8 af0 = *(const bf16x8*)&As[wm * 32 + ln][kk * 32 + quad * 8];
            bf16x8 af1 = *(const bf16x8*)&As[wm * 32 + 16 + ln][kk * 32 + quad * 8];
            bf16x8 bf0 = *(const bf16x8*)&Bs[wn * 32 + ln][kk * 32 + quad * 8];
            bf16x8 bf1 = *(const bf16x8*)&Bs[wn * 32 + 16 + ln][kk * 32 + quad * 8];
            acc[0][0] = __builtin_amdgcn_mfma_f32_16x16x32_bf16(af0, bf0, acc[0][0], 0, 0, 0);
            acc[0][1] = __builtin_amdgcn_mfma_f32_16x16x32_bf16(af0, bf1, acc[0][1], 0, 0, 0);
            acc[1][0] = __builtin_amdgcn_mfma_f32_16x16x32_bf16(af1, bf0, acc[1][0], 0, 0, 0);
            acc[1][1] = __builtin_amdgcn_mfma_f32_16x16x32_bf16(af1, bf1, acc[1][1], 0, 0, 0);
        }
    }

#pragma unroll
    for (int nt = 0; nt < 2; nt++) {
        int col = n0 + wn * 32 + nt * 16 + ln;
        float bz = bias[col];
#pragma unroll
        for (int mt = 0; mt < 2; mt++)
#pragma unroll
            for (int r = 0; r < 4; r++) {
                int row = m0 + wm * 32 + mt * 16 + quad * 4 + r;
                out[(long)row * 1024 + col] = acc[mt][nt][r] + bz;
            }
    }
}

extern "C" void kernel_launch(void* const* d_in, const int* in_sizes, int n_in,
                              void* d_out, int out_size, void* d_ws, size_t ws_size,
                              hipStream_t stream) {
    const float* q    = (const float*)d_in[0];
    const float* k    = (const float*)d_in[1];
    const float* v    = (const float*)d_in[2];
    const float* Wo_w = (const float*)d_in[3];
    const float* Wo_b = (const float*)d_in[4];
    float* out = (float*)d_out;

    unsigned short* wob  = (unsigned short*)d_ws;            // [1024][1024]   2 MB
    unsigned short* kbb  = wob + (size_t)1024 * 1024;        // [32][2048][64] 8.4 MB
    unsigned short* vtb  = kbb + (size_t)32 * 2048 * 64;     // [32][64][2048] 8.4 MB
    unsigned short* pbuf = vtb + (size_t)32 * 64 * 2048;     // [2048][64][64] 16.8 MB
    float*          lbuf = (float*)(pbuf + (size_t)2048 * 4096); // [2048][64]  0.5 MB

    prep_k<<<3072, 256, 0, stream>>>(k, v, Wo_w, kbb, vtb, wob);
    attn_k<<<2048, 256, 0, stream>>>(q, kbb, vtb, pbuf, lbuf);
    proj_k<<<1024, 256, 0, stream>>>(pbuf, lbuf, wob, Wo_b, out);
}